// Round 5
// baseline (123.346 us; speedup 1.0000x reference)
//
#include <hip/hip_runtime.h>
#include <math.h>

#define NA 131072
#define NBLK (NA/64)

typedef __bf16 bf16x8 __attribute__((ext_vector_type(8)));
typedef float f32x16 __attribute__((ext_vector_type(16)));

// ws byte offsets
#define APACK_OFF 0           // 19*11*64*16 = 214016 B  (GRU weight frags, K=176)
#define BIAS4_OFF 214016      // 152*16     = 2432 B     (r,z,hn,xn biases)
#define W1P_OFF   216448      // 2*13*64*16 = 26624 B
#define W2P_OFF   243072      // 2*4*64*16  = 8192 B     -> end 251264

__device__ __forceinline__ unsigned short f2b(float f){
  __bf16 h = (__bf16)f;
  unsigned short u;
  __builtin_memcpy(&u, &h, 2);
  return u;
}
__device__ __forceinline__ float b2f(unsigned short u){
  unsigned x = ((unsigned)u) << 16; float f;
  __builtin_memcpy(&f, &x, 4); return f;
}
__device__ __forceinline__ bf16x8 asb(uint4 u){ return __builtin_bit_cast(bf16x8, u); }
__device__ __forceinline__ f32x16 mfma32(bf16x8 a, bf16x8 b, f32x16 c){
  return __builtin_amdgcn_mfma_f32_32x32x16_bf16(a, b, c, 0, 0, 0);
}
__device__ __forceinline__ float fsigmoid(float x){ return 1.f/(1.f+__expf(-x)); }
__device__ __forceinline__ float ftanh(float x){ return 1.f - 2.f/(__expf(2.f*x)+1.f); }

// ---------------- prep: pack weights fragment-linear --------------------
// GRU K-mapping (K=176): k in [0,12) = x-part, [12,16) = 0,
// [16,166) = h-part (h index k-16), [166,176) = 0.
// A-frag: lane l holds A[mt*32+(l&31)][ks*16+(l>>5)*8+i], i=0..7.
// Row R = 4*j + g, g: 0=r 1=z 2=hn 3=xn.
__global__ __launch_bounds__(256) void prep2(
    const float* __restrict__ W_ih, const float* __restrict__ W_hh,
    const float* __restrict__ b_ih, const float* __restrict__ b_hh,
    const float* __restrict__ W1, const float* __restrict__ W2,
    float* __restrict__ ws)
{
  int tid = blockIdx.x*blockDim.x + threadIdx.x;
  int stride = gridDim.x*blockDim.x;
  unsigned short* Ap  = (unsigned short*)((char*)ws + APACK_OFF);
  float*          B4  = (float*)((char*)ws + BIAS4_OFF);
  unsigned short* W1p = (unsigned short*)((char*)ws + W1P_OFF);
  unsigned short* W2p = (unsigned short*)((char*)ws + W2P_OFF);

  for (int s = tid; s < 19*11*64; s += stride){
    int lane = s & 63; int t2 = s >> 6; int ks = t2 % 11; int mt = t2 / 11;
    int R = mt*32 + (lane & 31);
    int kb = ks*16 + (lane >> 5)*8;
    int j = R >> 2, g = R & 3;
    #pragma unroll
    for (int i=0;i<8;i++){
      int k = kb + i; float f = 0.f;
      if (j < 150){
        if (k < 12){
          if (g==0) f = W_ih[j*12+k];
          else if (g==1) f = W_ih[(150+j)*12+k];
          else if (g==3) f = W_ih[(300+j)*12+k];
        } else if (k >= 16 && k < 166){
          int kh = k - 16;
          if (g==0) f = W_hh[j*150+kh];
          else if (g==1) f = W_hh[(150+j)*150+kh];
          else if (g==2) f = W_hh[(300+j)*150+kh];
        }
      }
      Ap[s*8+i] = f2b(f);
    }
  }
  for (int j = tid; j < 152; j += stride){
    float4 bv = make_float4(0.f,0.f,0.f,0.f);
    if (j < 150){
      bv.x = b_ih[j]       + b_hh[j];
      bv.y = b_ih[150+j]   + b_hh[150+j];
      bv.z = b_hh[300+j];
      bv.w = b_ih[300+j];
    }
    ((float4*)B4)[j] = bv;
  }
  for (int s = tid; s < 2*13*64; s += stride){
    int lane = s & 63; int t2 = s >> 6; int ks = t2 % 13; int mt = t2 / 13;
    int o = mt*32 + (lane & 31);
    int kb = ks*16 + (lane >> 5)*8;
    #pragma unroll
    for (int i=0;i<8;i++){
      int k = kb + i;
      float f = (o < 50 && k < 200) ? W1[o*200+k] : 0.f;
      W1p[s*8+i] = f2b(f);
    }
  }
  for (int s = tid; s < 2*4*64; s += stride){
    int lane = s & 63; int t2 = s >> 6; int ks = t2 % 4; int mt = t2 / 4;
    int o = mt*32 + (lane & 31);
    int kb = ks*16 + (lane >> 5)*8;
    #pragma unroll
    for (int i=0;i<8;i++){
      int k = kb + i;
      float f = (o < 50 && k < 50) ? W2[o*50+k] : 0.f;
      W2p[s*8+i] = f2b(f);
    }
  }
}

// ---------------- fused GRU + MLP + head -------------------------------
// LDS (36864 B total, aliased):
//   [0, 27648)      sm_ag  u16[64][216]  agent rows [h(150)|static(50)|pad]
//                   sm_h2  f32[64][51]   (aliases sm_ag after MLP1)
//   [27648, 36864)  sm_xf  u16[2][64][8] x frags (dead after frag build)
//                   sm_h1  u16[64][72]   (aliases sm_xf after frag build)
__global__ __launch_bounds__(256,4) void fused_kernel(
    const float* __restrict__ x_flat, const float* __restrict__ h_in,
    const float* __restrict__ st, const float* __restrict__ z_in,
    const float* __restrict__ dx, const float* __restrict__ xp,
    const float* __restrict__ b1, const float* __restrict__ b2,
    const float* __restrict__ W3, const float* __restrict__ b3,
    const unsigned short* __restrict__ Apack, const float* __restrict__ Bias4,
    const unsigned short* __restrict__ W1p, const unsigned short* __restrict__ W2p,
    float* __restrict__ out)
{
  __shared__ char smem[36864];
  unsigned short* sm_ag = (unsigned short*)smem;           // [64][216]
  unsigned short* sm_xf = (unsigned short*)(smem + 27648); // [2][64][8]
  unsigned short* sm_h1 = (unsigned short*)(smem + 27648); // [64][72]
  float*          sm_h2 = (float*)smem;                    // [64][51]
  unsigned*       ag32  = (unsigned*)sm_ag;

  int t = threadIdx.x; int lane = t & 63; int w = t >> 6;
  int hi = lane >> 5, cl = lane & 31;
  long ab = (long)blockIdx.x * 64;

  // stage h (coalesced float2 -> packed bf16), row cols 0..149
  const float2* h2p = (const float2*)h_in;
  for (int s = t; s < 4800; s += 256){
    int a = s/75, k2 = s - a*75;
    float2 v = h2p[ab*75 + s];
    ag32[a*108 + k2] = (unsigned)f2b(v.x) | ((unsigned)f2b(v.y) << 16);
  }
  // stage static, row cols 150..199
  const float2* s2p = (const float2*)st;
  for (int s = t; s < 1600; s += 256){
    int a = s/25, k2 = s - a*25;
    float2 v = s2p[ab*25 + s];
    ag32[a*108 + 75 + k2] = (unsigned)f2b(v.x) | ((unsigned)f2b(v.y) << 16);
  }
  // zero row pad (cols 200..215) — MLP1 ks=12 reads cols 192..207; the
  // weights there are zero but 0 x uninitialized-NaN = NaN, so pad MUST be 0.
  for (int s = t; s < 512; s += 256)
    ag32[(s>>3)*108 + 100 + (s&7)] = 0u;
  // stage x directly fragment-linear: sm_xf[nt][lane][i] = B[k=(lane>>5)*8+i][nt*32+(lane&31)]
  for (int s = t; s < 1024; s += 256){
    int nt2 = s >> 9; int r = s & 511; int ln = r >> 3; int i = r & 7;
    int k = ((ln >> 5) << 3) + i;
    int agent = nt2*32 + (ln & 31);
    unsigned short v = 0;
    if (k < 12) v = f2b(x_flat[(ab+agent)*12 + k]);
    sm_xf[s] = v;
  }
  __syncthreads();

  // ---- GRU B-frags: 22 clean ds_read_b128 per thread ----
  bf16x8 B0[11], B1[11];
  {
    B0[0] = asb(((const uint4*)sm_xf)[lane]);
    B1[0] = asb(((const uint4*)sm_xf)[64 + lane]);
    const uint4* r0 = (const uint4*)(sm_ag + cl*216);
    const uint4* r1 = (const uint4*)(sm_ag + (32+cl)*216);
    #pragma unroll
    for (int ks=1; ks<11; ks++){
      B0[ks] = asb(r0[(ks-1)*2 + hi]);
      B1[ks] = asb(r1[(ks-1)*2 + hi]);
    }
  }
  __syncthreads();   // frag reads done: sm_xf dead, in-place h_new writes allowed

  // zero sm_h1 (cols 50..71 serve as MLP2 K-pad)
  for (int s = t; s < 2304; s += 256) ((unsigned*)sm_h1)[s] = 0u;

  // ---- GRU MFMA + gate epilogue (h_new in place, bf16) ----
  const uint4* ApV = (const uint4*)Apack;
  #pragma unroll 1
  for (int mt = w; mt < 19; mt += 4){
    f32x16 acc0;
    #pragma unroll
    for (int q=0;q<4;q++){
      float4 bq = ((const float4*)Bias4)[mt*8 + 2*q + hi];
      acc0[4*q+0]=bq.x; acc0[4*q+1]=bq.y; acc0[4*q+2]=bq.z; acc0[4*q+3]=bq.w;
    }
    f32x16 acc1 = acc0;
    const uint4* ap = ApV + (size_t)(mt*11)*64 + lane;
    #pragma unroll
    for (int ks=0; ks<11; ks++){
      bf16x8 af = asb(ap[ks*64]);
      acc0 = mfma32(af, B0[ks], acc0);
      acc1 = mfma32(af, B1[ks], acc1);
    }
    #pragma unroll
    for (int nt=0; nt<2; nt++){
      const f32x16& acc = nt ? acc1 : acc0;
      int a = nt*32 + cl;
      #pragma unroll
      for (int q=0;q<4;q++){
        int j = mt*8 + 2*q + hi;
        if (j < 150){
          float h0 = b2f(sm_ag[a*216 + j]);
          float r = fsigmoid(acc[4*q+0]);
          float z = fsigmoid(acc[4*q+1]);
          float n = ftanh(acc[4*q+3] + r*acc[4*q+2]);
          sm_ag[a*216 + j] = f2b(n + z*(h0 - n));
        }
      }
    }
  }
  __syncthreads();

  // ---- flush h_new coalesced ----
  float2* oh2 = (float2*)(out + (size_t)8*NA);
  for (int s = t; s < 4800; s += 256){
    int a = s/75, k2 = s - a*75;
    unsigned u = ag32[a*108 + k2];
    float2 v; v.x = b2f((unsigned short)u); v.y = b2f((unsigned short)(u>>16));
    oh2[ab*75 + s] = v;
  }

  // ---- MLP1: 200 -> 50, softplus ----
  int mt2 = w >> 1; int a2 = (w & 1)*32 + cl;
  f32x16 acc;
  #pragma unroll
  for (int r=0;r<16;r++){
    int o = mt2*32 + (r&3) + 8*(r>>2) + 4*hi;
    acc[r] = (o < 50) ? b1[o] : 0.f;
  }
  {
    const uint4* rv  = (const uint4*)(sm_ag + a2*216);
    const uint4* w1v = (const uint4*)W1p;
    #pragma unroll
    for (int ks=0; ks<13; ks++){
      acc = mfma32(asb(w1v[(mt2*13+ks)*64 + lane]), asb(rv[ks*2+hi]), acc);
    }
  }
  #pragma unroll
  for (int r=0;r<16;r++){
    int o = mt2*32 + (r&3) + 8*(r>>2) + 4*hi;
    if (o < 50){
      float xx = acc[r];
      float spv = fmaxf(xx,0.f) + __logf(1.f + __expf(-fabsf(xx)));
      sm_h1[a2*72 + o] = f2b(spv);
    }
  }
  __syncthreads();

  // ---- MLP2: 50 -> 50, tanh ----
  f32x16 acc2;
  #pragma unroll
  for (int r=0;r<16;r++){
    int o = mt2*32 + (r&3) + 8*(r>>2) + 4*hi;
    acc2[r] = (o < 50) ? b2[o] : 0.f;
  }
  {
    const uint4* r1v = (const uint4*)(sm_h1 + a2*72);
    const uint4* w2v = (const uint4*)W2p;
    #pragma unroll
    for (int ks=0; ks<4; ks++){
      acc2 = mfma32(asb(w2v[(mt2*4+ks)*64 + lane]), asb(r1v[ks*2+hi]), acc2);
    }
  }
  #pragma unroll
  for (int r=0;r<16;r++){
    int o = mt2*32 + (r&3) + 8*(r>>2) + 4*hi;
    if (o < 50) sm_h2[a2*51 + o] = ftanh(acc2[r]);
  }
  __syncthreads();

  // ---- head: 50 -> 6 + distribution math ----
  if (t < 64){
    int a = t; long ga = ab + a;
    float o6[6];
    #pragma unroll
    for (int jj=0;jj<6;jj++) o6[jj] = b3[jj];
    for (int k=0;k<50;k++){
      float v = sm_h2[a*51 + k];
      #pragma unroll
      for (int jj=0;jj<6;jj++) o6[jj] = fmaf(v, W3[jj*50+k], o6[jj]);
    }
    float mu0 = xp[ga*2+0] + 0.5f*dx[ga*2+0] + o6[0];
    float mu1 = xp[ga*2+1] + 0.5f*dx[ga*2+1] + o6[1];
    float bb  = o6[3] + o6[4];
    float apd = o6[2] + o6[5];
    float amd = o6[2] - o6[5];
    float delta = sqrtf(amd*amd + bb*bb);
    float e  = __expf(delta);
    float ei = 1.f/e;
    float sinh_ = 0.5f*(e - ei);
    float cosh_ = 0.5f*(e + ei);
    float tmp1 = sinh_/delta;
    float tmp2 = amd/tmp1;
    float ea = __expf(apd);
    float s00 = (cosh_+tmp2)*ea;
    float s01 = (bb*tmp1)*ea;
    float s11 = (cosh_-tmp2)*ea;
    float z0 = z_in[ga*2+0], z1 = z_in[ga*2+1];
    out[ga*2+0] = s00*z0 + s01*z1 + mu0;
    out[ga*2+1] = s01*z0 + s11*z1 + mu1;
    out[(size_t)2*NA + ga*2+0] = mu0;
    out[(size_t)2*NA + ga*2+1] = mu1;
    out[(size_t)4*NA + ga*4+0] = s00;
    out[(size_t)4*NA + ga*4+1] = s01;
    out[(size_t)4*NA + ga*4+2] = s01;
    out[(size_t)4*NA + ga*4+3] = s11;
  }
}

extern "C" void kernel_launch(void* const* d_in, const int* in_sizes, int n_in,
                              void* d_out, int out_size, void* d_ws, size_t ws_size,
                              hipStream_t stream) {
  const float* z      = (const float*)d_in[0];
  const float* x_flat = (const float*)d_in[1];
  const float* h      = (const float*)d_in[2];
  const float* st     = (const float*)d_in[3];
  const float* dx     = (const float*)d_in[4];
  const float* xp     = (const float*)d_in[5];
  const float* W_ih   = (const float*)d_in[6];
  const float* W_hh   = (const float*)d_in[7];
  const float* b_ih   = (const float*)d_in[8];
  const float* b_hh   = (const float*)d_in[9];
  const float* W1     = (const float*)d_in[10];
  const float* b1     = (const float*)d_in[11];
  const float* W2     = (const float*)d_in[12];
  const float* b2     = (const float*)d_in[13];
  const float* W3     = (const float*)d_in[14];
  const float* b3     = (const float*)d_in[15];
  float* out = (float*)d_out;
  float* ws  = (float*)d_ws;

  const unsigned short* Apack = (const unsigned short*)((char*)ws + APACK_OFF);
  const float*          Bias4 = (const float*)((char*)ws + BIAS4_OFF);
  const unsigned short* W1p   = (const unsigned short*)((char*)ws + W1P_OFF);
  const unsigned short* W2p   = (const unsigned short*)((char*)ws + W2P_OFF);

  hipLaunchKernelGGL(prep2, dim3(128), dim3(256), 0, stream,
                     W_ih, W_hh, b_ih, b_hh, W1, W2, ws);
  hipLaunchKernelGGL(fused_kernel, dim3(NBLK), dim3(256), 0, stream,
                     x_flat, h, st, z, dx, xp, b1, b2, W3, b3,
                     Apack, Bias4, W1p, W2p, out);
}

// Round 9
// 110.213 us; speedup vs baseline: 1.1192x; 1.1192x over previous
//
#include <hip/hip_runtime.h>
#include <math.h>

#define NA 131072
#define NBLK (NA/64)

typedef __bf16 bf16x8 __attribute__((ext_vector_type(8)));
typedef float f32x16 __attribute__((ext_vector_type(16)));

// ws byte offsets
#define APACK_OFF 0           // 19*11*64*16 = 214016 B  (GRU weight frags, K=176)
#define BIAS4_OFF 214016      // 152*16     = 2432 B     (r,z,hn,xn biases)
#define W1P_OFF   216448      // 2*13*64*16 = 26624 B    (K=208: h(150)|static(50)|pad(8))
#define W2P_OFF   243072      // 2*4*64*16  = 8192 B     -> end 251264

__device__ __forceinline__ unsigned short f2b(float f){
  __bf16 h = (__bf16)f;
  unsigned short u;
  __builtin_memcpy(&u, &h, 2);
  return u;
}
__device__ __forceinline__ float b2f(unsigned short u){
  unsigned x = ((unsigned)u) << 16; float f;
  __builtin_memcpy(&f, &x, 4); return f;
}
__device__ __forceinline__ bf16x8 asb(uint4 u){ return __builtin_bit_cast(bf16x8, u); }
__device__ __forceinline__ f32x16 mfma32(bf16x8 a, bf16x8 b, f32x16 c){
  return __builtin_amdgcn_mfma_f32_32x32x16_bf16(a, b, c, 0, 0, 0);
}
__device__ __forceinline__ float fsigmoid(float x){ return 1.f/(1.f+__expf(-x)); }
__device__ __forceinline__ float ftanh(float x){ return 1.f - 2.f/(__expf(2.f*x)+1.f); }

// ---------------- prep: pack weights fragment-linear --------------------
// GRU K-map (K=176): k in [0,12)=x, [12,16)=0, [16,166)=h[k-16], [166,176)=0.
// MLP1 K-map (K=208): k<200 -> W1[o][k] (row = [h|static] contiguous,
//                     matching sm_ag layout), k in [200,208) -> 0.
// A-frag: lane l holds A[mt*32+(l&31)][ks*16+(l>>5)*8+i], i=0..7.
// Row R = 4*j + g, g: 0=r 1=z 2=hn 3=xn.
__global__ __launch_bounds__(256) void prep2(
    const float* __restrict__ W_ih, const float* __restrict__ W_hh,
    const float* __restrict__ b_ih, const float* __restrict__ b_hh,
    const float* __restrict__ W1, const float* __restrict__ W2,
    float* __restrict__ ws)
{
  int tid = blockIdx.x*blockDim.x + threadIdx.x;
  int stride = gridDim.x*blockDim.x;
  unsigned short* Ap  = (unsigned short*)((char*)ws + APACK_OFF);
  float*          B4  = (float*)((char*)ws + BIAS4_OFF);
  unsigned short* W1p = (unsigned short*)((char*)ws + W1P_OFF);
  unsigned short* W2p = (unsigned short*)((char*)ws + W2P_OFF);

  for (int s = tid; s < 19*11*64; s += stride){
    int lane = s & 63; int t2 = s >> 6; int ks = t2 % 11; int mt = t2 / 11;
    int R = mt*32 + (lane & 31);
    int kb = ks*16 + (lane >> 5)*8;
    int j = R >> 2, g = R & 3;
    #pragma unroll
    for (int i=0;i<8;i++){
      int k = kb + i; float f = 0.f;
      if (j < 150){
        if (k < 12){
          if (g==0) f = W_ih[j*12+k];
          else if (g==1) f = W_ih[(150+j)*12+k];
          else if (g==3) f = W_ih[(300+j)*12+k];
        } else if (k >= 16 && k < 166){
          int kh = k - 16;
          if (g==0) f = W_hh[j*150+kh];
          else if (g==1) f = W_hh[(150+j)*150+kh];
          else if (g==2) f = W_hh[(300+j)*150+kh];
        }
      }
      Ap[s*8+i] = f2b(f);
    }
  }
  for (int j = tid; j < 152; j += stride){
    float4 bv = make_float4(0.f,0.f,0.f,0.f);
    if (j < 150){
      bv.x = b_ih[j]       + b_hh[j];
      bv.y = b_ih[150+j]   + b_hh[150+j];
      bv.z = b_hh[300+j];
      bv.w = b_ih[300+j];
    }
    ((float4*)B4)[j] = bv;
  }
  for (int s = tid; s < 2*13*64; s += stride){
    int lane = s & 63; int t2 = s >> 6; int ks = t2 % 13; int mt = t2 / 13;
    int o = mt*32 + (lane & 31);
    int kb = ks*16 + (lane >> 5)*8;
    #pragma unroll
    for (int i=0;i<8;i++){
      int k = kb + i;
      // CONTIGUOUS map: row = [h(0..149)|static(150..199)], pad 200..207 = 0.
      float f = (o < 50 && k < 200) ? W1[o*200+k] : 0.f;
      W1p[s*8+i] = f2b(f);
    }
  }
  for (int s = tid; s < 2*4*64; s += stride){
    int lane = s & 63; int t2 = s >> 6; int ks = t2 % 4; int mt = t2 / 4;
    int o = mt*32 + (lane & 31);
    int kb = ks*16 + (lane >> 5)*8;
    #pragma unroll
    for (int i=0;i<8;i++){
      int k = kb + i;
      float f = (o < 50 && k < 50) ? W2[o*50+k] : 0.f;
      W2p[s*8+i] = f2b(f);
    }
  }
}

// ---------------- fused GRU + MLP + head -------------------------------
// LDS (36864 B total, aliased) — identical to the round-5 PASSING kernel;
// only the launch-bounds register budget changed (4 -> 3 waves/EU) so the
// 22 cached B-frags (88 VGPR) fit without spilling.
//   [0, 27648)      sm_ag  u16[64][216]  agent rows [h(150)|static(50)|pad]
//                   sm_h2  f32[64][51]   (aliases sm_ag after MLP1)
//   [27648, 36864)  sm_xf  u16[2][64][8] x frags (dead after frag build)
//                   sm_h1  u16[64][72]   (aliases sm_xf after frag build)
__global__ __launch_bounds__(256,3) void fused_kernel(
    const float* __restrict__ x_flat, const float* __restrict__ h_in,
    const float* __restrict__ st, const float* __restrict__ z_in,
    const float* __restrict__ dx, const float* __restrict__ xp,
    const float* __restrict__ b1, const float* __restrict__ b2,
    const float* __restrict__ W3, const float* __restrict__ b3,
    const unsigned short* __restrict__ Apack, const float* __restrict__ Bias4,
    const unsigned short* __restrict__ W1p, const unsigned short* __restrict__ W2p,
    float* __restrict__ out)
{
  __shared__ char smem[36864];
  unsigned short* sm_ag = (unsigned short*)smem;           // [64][216]
  unsigned short* sm_xf = (unsigned short*)(smem + 27648); // [2][64][8]
  unsigned short* sm_h1 = (unsigned short*)(smem + 27648); // [64][72]
  float*          sm_h2 = (float*)smem;                    // [64][51]
  unsigned*       ag32  = (unsigned*)sm_ag;

  int t = threadIdx.x; int lane = t & 63; int w = t >> 6;
  int hi = lane >> 5, cl = lane & 31;
  long ab = (long)blockIdx.x * 64;

  // stage h (coalesced float2 -> packed bf16), row cols 0..149
  const float2* h2p = (const float2*)h_in;
  for (int s = t; s < 4800; s += 256){
    int a = s/75, k2 = s - a*75;
    float2 v = h2p[ab*75 + s];
    ag32[a*108 + k2] = (unsigned)f2b(v.x) | ((unsigned)f2b(v.y) << 16);
  }
  // stage static, row cols 150..199
  const float2* s2p = (const float2*)st;
  for (int s = t; s < 1600; s += 256){
    int a = s/25, k2 = s - a*25;
    float2 v = s2p[ab*25 + s];
    ag32[a*108 + 75 + k2] = (unsigned)f2b(v.x) | ((unsigned)f2b(v.y) << 16);
  }
  // zero row pad (cols 200..215) — MLP1 ks=12 reads cols 192..207; the
  // weights there are zero but 0 x uninitialized-NaN = NaN, so pad MUST be 0.
  for (int s = t; s < 512; s += 256)
    ag32[(s>>3)*108 + 100 + (s&7)] = 0u;
  // stage x directly fragment-linear: sm_xf[nt][lane][i] = B[k=(lane>>5)*8+i][nt*32+(lane&31)]
  for (int s = t; s < 1024; s += 256){
    int nt2 = s >> 9; int r = s & 511; int ln = r >> 3; int i = r & 7;
    int k = ((ln >> 5) << 3) + i;
    int agent = nt2*32 + (ln & 31);
    unsigned short v = 0;
    if (k < 12) v = f2b(x_flat[(ab+agent)*12 + k]);
    sm_xf[s] = v;
  }
  __syncthreads();

  // ---- GRU B-frags: 22 clean ds_read_b128 per thread, cached in regs ----
  bf16x8 B0[11], B1[11];
  {
    B0[0] = asb(((const uint4*)sm_xf)[lane]);
    B1[0] = asb(((const uint4*)sm_xf)[64 + lane]);
    const uint4* r0 = (const uint4*)(sm_ag + cl*216);
    const uint4* r1 = (const uint4*)(sm_ag + (32+cl)*216);
    #pragma unroll
    for (int ks=1; ks<11; ks++){
      B0[ks] = asb(r0[(ks-1)*2 + hi]);
      B1[ks] = asb(r1[(ks-1)*2 + hi]);
    }
  }
  __syncthreads();   // frag reads done: sm_xf dead, in-place h_new writes allowed

  // zero sm_h1 (cols 50..71 serve as MLP2 K-pad)
  for (int s = t; s < 2304; s += 256) ((unsigned*)sm_h1)[s] = 0u;

  // ---- GRU MFMA + gate epilogue (h_new in place, bf16) ----
  const uint4* ApV = (const uint4*)Apack;
  #pragma unroll 1
  for (int mt = w; mt < 19; mt += 4){
    f32x16 acc0;
    #pragma unroll
    for (int q=0;q<4;q++){
      float4 bq = ((const float4*)Bias4)[mt*8 + 2*q + hi];
      acc0[4*q+0]=bq.x; acc0[4*q+1]=bq.y; acc0[4*q+2]=bq.z; acc0[4*q+3]=bq.w;
    }
    f32x16 acc1 = acc0;
    const uint4* ap = ApV + (size_t)(mt*11)*64 + lane;
    #pragma unroll
    for (int ks=0; ks<11; ks++){
      bf16x8 af = asb(ap[ks*64]);
      acc0 = mfma32(af, B0[ks], acc0);
      acc1 = mfma32(af, B1[ks], acc1);
    }
    #pragma unroll
    for (int nt=0; nt<2; nt++){
      const f32x16& acc = nt ? acc1 : acc0;
      int a = nt*32 + cl;
      #pragma unroll
      for (int q=0;q<4;q++){
        int j = mt*8 + 2*q + hi;
        if (j < 150){
          float h0 = b2f(sm_ag[a*216 + j]);
          float r = fsigmoid(acc[4*q+0]);
          float z = fsigmoid(acc[4*q+1]);
          float n = ftanh(acc[4*q+3] + r*acc[4*q+2]);
          sm_ag[a*216 + j] = f2b(n + z*(h0 - n));
        }
      }
    }
  }
  __syncthreads();

  // ---- flush h_new coalesced ----
  float2* oh2 = (float2*)(out + (size_t)8*NA);
  for (int s = t; s < 4800; s += 256){
    int a = s/75, k2 = s - a*75;
    unsigned u = ag32[a*108 + k2];
    float2 v; v.x = b2f((unsigned short)u); v.y = b2f((unsigned short)(u>>16));
    oh2[ab*75 + s] = v;
  }

  // ---- MLP1: 200 -> 50, softplus ----
  int mt2 = w >> 1; int a2 = (w & 1)*32 + cl;
  f32x16 acc;
  #pragma unroll
  for (int r=0;r<16;r++){
    int o = mt2*32 + (r&3) + 8*(r>>2) + 4*hi;
    acc[r] = (o < 50) ? b1[o] : 0.f;
  }
  {
    const uint4* rv  = (const uint4*)(sm_ag + a2*216);
    const uint4* w1v = (const uint4*)W1p;
    #pragma unroll
    for (int ks=0; ks<13; ks++){
      acc = mfma32(asb(w1v[(mt2*13+ks)*64 + lane]), asb(rv[ks*2+hi]), acc);
    }
  }
  #pragma unroll
  for (int r=0;r<16;r++){
    int o = mt2*32 + (r&3) + 8*(r>>2) + 4*hi;
    if (o < 50){
      float xx = acc[r];
      float spv = fmaxf(xx,0.f) + __logf(1.f + __expf(-fabsf(xx)));
      sm_h1[a2*72 + o] = f2b(spv);
    }
  }
  __syncthreads();

  // ---- MLP2: 50 -> 50, tanh ----
  f32x16 acc2;
  #pragma unroll
  for (int r=0;r<16;r++){
    int o = mt2*32 + (r&3) + 8*(r>>2) + 4*hi;
    acc2[r] = (o < 50) ? b2[o] : 0.f;
  }
  {
    const uint4* r1v = (const uint4*)(sm_h1 + a2*72);
    const uint4* w2v = (const uint4*)W2p;
    #pragma unroll
    for (int ks=0; ks<4; ks++){
      acc2 = mfma32(asb(w2v[(mt2*4+ks)*64 + lane]), asb(r1v[ks*2+hi]), acc2);
    }
  }
  #pragma unroll
  for (int r=0;r<16;r++){
    int o = mt2*32 + (r&3) + 8*(r>>2) + 4*hi;
    if (o < 50) sm_h2[a2*51 + o] = ftanh(acc2[r]);
  }
  __syncthreads();

  // ---- head: 50 -> 6 + distribution math ----
  if (t < 64){
    int a = t; long ga = ab + a;
    float o6[6];
    #pragma unroll
    for (int jj=0;jj<6;jj++) o6[jj] = b3[jj];
    for (int k=0;k<50;k++){
      float v = sm_h2[a*51 + k];
      #pragma unroll
      for (int jj=0;jj<6;jj++) o6[jj] = fmaf(v, W3[jj*50+k], o6[jj]);
    }
    float mu0 = xp[ga*2+0] + 0.5f*dx[ga*2+0] + o6[0];
    float mu1 = xp[ga*2+1] + 0.5f*dx[ga*2+1] + o6[1];
    float bb  = o6[3] + o6[4];
    float apd = o6[2] + o6[5];
    float amd = o6[2] - o6[5];
    float delta = sqrtf(amd*amd + bb*bb);
    float e  = __expf(delta);
    float ei = 1.f/e;
    float sinh_ = 0.5f*(e - ei);
    float cosh_ = 0.5f*(e + ei);
    float tmp1 = sinh_/delta;
    float tmp2 = amd/tmp1;
    float ea = __expf(apd);
    float s00 = (cosh_+tmp2)*ea;
    float s01 = (bb*tmp1)*ea;
    float s11 = (cosh_-tmp2)*ea;
    float z0 = z_in[ga*2+0], z1 = z_in[ga*2+1];
    out[ga*2+0] = s00*z0 + s01*z1 + mu0;
    out[ga*2+1] = s01*z0 + s11*z1 + mu1;
    out[(size_t)2*NA + ga*2+0] = mu0;
    out[(size_t)2*NA + ga*2+1] = mu1;
    out[(size_t)4*NA + ga*4+0] = s00;
    out[(size_t)4*NA + ga*4+1] = s01;
    out[(size_t)4*NA + ga*4+2] = s01;
    out[(size_t)4*NA + ga*4+3] = s11;
  }
}

extern "C" void kernel_launch(void* const* d_in, const int* in_sizes, int n_in,
                              void* d_out, int out_size, void* d_ws, size_t ws_size,
                              hipStream_t stream) {
  const float* z      = (const float*)d_in[0];
  const float* x_flat = (const float*)d_in[1];
  const float* h      = (const float*)d_in[2];
  const float* st     = (const float*)d_in[3];
  const float* dx     = (const float*)d_in[4];
  const float* xp     = (const float*)d_in[5];
  const float* W_ih   = (const float*)d_in[6];
  const float* W_hh   = (const float*)d_in[7];
  const float* b_ih   = (const float*)d_in[8];
  const float* b_hh   = (const float*)d_in[9];
  const float* W1     = (const float*)d_in[10];
  const float* b1     = (const float*)d_in[11];
  const float* W2     = (const float*)d_in[12];
  const float* b2     = (const float*)d_in[13];
  const float* W3     = (const float*)d_in[14];
  const float* b3     = (const float*)d_in[15];
  float* out = (float*)d_out;
  float* ws  = (float*)d_ws;

  const unsigned short* Apack = (const unsigned short*)((char*)ws + APACK_OFF);
  const float*          Bias4 = (const float*)((char*)ws + BIAS4_OFF);
  const unsigned short* W1p   = (const unsigned short*)((char*)ws + W1P_OFF);
  const unsigned short* W2p   = (const unsigned short*)((char*)ws + W2P_OFF);

  hipLaunchKernelGGL(prep2, dim3(128), dim3(256), 0, stream,
                     W_ih, W_hh, b_ih, b_hh, W1, W2, ws);
  hipLaunchKernelGGL(fused_kernel, dim3(NBLK), dim3(256), 0, stream,
                     x_flat, h, st, z, dx, xp, b1, b2, W3, b3,
                     Apack, Bias4, W1p, W2p, out);
}

// Round 12
// 109.572 us; speedup vs baseline: 1.1257x; 1.0058x over previous
//
#include <hip/hip_runtime.h>
#include <math.h>

#define NA 131072
#define NBLK32 (NA/32)

typedef __bf16 bf16x8 __attribute__((ext_vector_type(8)));
typedef float f32x16 __attribute__((ext_vector_type(16)));

// ws byte offsets
#define APACK_OFF 0           // 19*11*64*16 = 214016 B  (GRU weight frags, K=176)
#define BIAS4_OFF 214016      // 152*16     = 2432 B     (r,z,hn,xn biases)
#define W1P_OFF   216448      // 2*13*64*16 = 26624 B    (K=208: [h|static] contiguous)
#define W2P_OFF   243072      // 2*4*64*16  = 8192 B     -> end 251264

__device__ __forceinline__ unsigned short f2b(float f){
  __bf16 h = (__bf16)f;
  unsigned short u;
  __builtin_memcpy(&u, &h, 2);
  return u;
}
__device__ __forceinline__ float b2f(unsigned short u){
  unsigned x = ((unsigned)u) << 16; float f;
  __builtin_memcpy(&f, &x, 4); return f;
}
__device__ __forceinline__ bf16x8 asb(uint4 u){ return __builtin_bit_cast(bf16x8, u); }
__device__ __forceinline__ f32x16 mfma32(bf16x8 a, bf16x8 b, f32x16 c){
  return __builtin_amdgcn_mfma_f32_32x32x16_bf16(a, b, c, 0, 0, 0);
}
__device__ __forceinline__ float fsigmoid(float x){ return 1.f/(1.f+__expf(-x)); }
__device__ __forceinline__ float ftanh(float x){ return 1.f - 2.f/(__expf(2.f*x)+1.f); }

// ---------------- prep: pack weights fragment-linear (unchanged, proven) ----
// GRU K-map (K=176): k in [0,12)=x, [12,16)=0, [16,166)=h[k-16], [166,176)=0.
// MLP1 K-map (K=208): k<200 -> W1[o][k] (row = [h|static] contiguous), else 0.
__global__ __launch_bounds__(256) void prep2(
    const float* __restrict__ W_ih, const float* __restrict__ W_hh,
    const float* __restrict__ b_ih, const float* __restrict__ b_hh,
    const float* __restrict__ W1, const float* __restrict__ W2,
    float* __restrict__ ws)
{
  int tid = blockIdx.x*blockDim.x + threadIdx.x;
  int stride = gridDim.x*blockDim.x;
  unsigned short* Ap  = (unsigned short*)((char*)ws + APACK_OFF);
  float*          B4  = (float*)((char*)ws + BIAS4_OFF);
  unsigned short* W1p = (unsigned short*)((char*)ws + W1P_OFF);
  unsigned short* W2p = (unsigned short*)((char*)ws + W2P_OFF);

  for (int s = tid; s < 19*11*64; s += stride){
    int lane = s & 63; int t2 = s >> 6; int ks = t2 % 11; int mt = t2 / 11;
    int R = mt*32 + (lane & 31);
    int kb = ks*16 + (lane >> 5)*8;
    int j = R >> 2, g = R & 3;
    #pragma unroll
    for (int i=0;i<8;i++){
      int k = kb + i; float f = 0.f;
      if (j < 150){
        if (k < 12){
          if (g==0) f = W_ih[j*12+k];
          else if (g==1) f = W_ih[(150+j)*12+k];
          else if (g==3) f = W_ih[(300+j)*12+k];
        } else if (k >= 16 && k < 166){
          int kh = k - 16;
          if (g==0) f = W_hh[j*150+kh];
          else if (g==1) f = W_hh[(150+j)*150+kh];
          else if (g==2) f = W_hh[(300+j)*150+kh];
        }
      }
      Ap[s*8+i] = f2b(f);
    }
  }
  for (int j = tid; j < 152; j += stride){
    float4 bv = make_float4(0.f,0.f,0.f,0.f);
    if (j < 150){
      bv.x = b_ih[j]       + b_hh[j];
      bv.y = b_ih[150+j]   + b_hh[150+j];
      bv.z = b_hh[300+j];
      bv.w = b_ih[300+j];
    }
    ((float4*)B4)[j] = bv;
  }
  for (int s = tid; s < 2*13*64; s += stride){
    int lane = s & 63; int t2 = s >> 6; int ks = t2 % 13; int mt = t2 / 13;
    int o = mt*32 + (lane & 31);
    int kb = ks*16 + (lane >> 5)*8;
    #pragma unroll
    for (int i=0;i<8;i++){
      int k = kb + i;
      float f = (o < 50 && k < 200) ? W1[o*200+k] : 0.f;
      W1p[s*8+i] = f2b(f);
    }
  }
  for (int s = tid; s < 2*4*64; s += stride){
    int lane = s & 63; int t2 = s >> 6; int ks = t2 % 4; int mt = t2 / 4;
    int o = mt*32 + (lane & 31);
    int kb = ks*16 + (lane >> 5)*8;
    #pragma unroll
    for (int i=0;i<8;i++){
      int k = kb + i;
      float f = (o < 50 && k < 50) ? W2[o*50+k] : 0.f;
      W2p[s*8+i] = f2b(f);
    }
  }
}

// ---------------- fused GRU + MLP + head: 32 agents/block ----------------
// Round-9 dataflow exactly (all frags pre-cached, in-place h_new, scalar
// guarded epilogue writes), minus the second ntile -> fits (256,4).
// LDS (18432 B, aliased):
//   [0, 13824)      sm_ag u16[32][216] rows [h(150)|static(50)|pad(16)]
//                   sm_h2 f32[32][51]  aliases sm_ag after MLP1
//   [13824, 18432)  sm_xf u16[64][8]   x frags (dead after frag build)
//                   sm_h1 u16[32][72]  aliases sm_xf after frag build
__global__ __launch_bounds__(256,4) void fused_kernel(
    const float* __restrict__ x_flat, const float* __restrict__ h_in,
    const float* __restrict__ st, const float* __restrict__ z_in,
    const float* __restrict__ dx, const float* __restrict__ xp,
    const float* __restrict__ b1, const float* __restrict__ b2,
    const float* __restrict__ W3, const float* __restrict__ b3,
    const unsigned short* __restrict__ Apack, const float* __restrict__ Bias4,
    const unsigned short* __restrict__ W1p, const unsigned short* __restrict__ W2p,
    float* __restrict__ out)
{
  __shared__ char smem[18432];
  unsigned short* sm_ag = (unsigned short*)smem;           // [32][216]
  unsigned short* sm_xf = (unsigned short*)(smem + 13824); // [64][8]
  unsigned short* sm_h1 = (unsigned short*)(smem + 13824); // [32][72]
  float*          sm_h2 = (float*)smem;                    // [32][51]
  unsigned*       ag32  = (unsigned*)sm_ag;

  int t = threadIdx.x; int lane = t & 63; int w = t >> 6;
  int hi = lane >> 5, cl = lane & 31;
  long ab = (long)blockIdx.x * 32;

  // stage h (coalesced float2 -> packed bf16), row cols 0..149
  const float2* h2p = (const float2*)h_in;
  for (int s = t; s < 2400; s += 256){
    int a = s/75, k2 = s - a*75;
    float2 v = h2p[ab*75 + s];
    ag32[a*108 + k2] = (unsigned)f2b(v.x) | ((unsigned)f2b(v.y) << 16);
  }
  // stage static, row cols 150..199
  const float2* s2p = (const float2*)st;
  for (int s = t; s < 800; s += 256){
    int a = s/25, k2 = s - a*25;
    float2 v = s2p[ab*25 + s];
    ag32[a*108 + 75 + k2] = (unsigned)f2b(v.x) | ((unsigned)f2b(v.y) << 16);
  }
  // zero row pad (cols 200..215): MLP1 ks=12 reads cols 192..207; pad MUST be 0
  if (t < 256){
    int s = t;
    if (s < 256) ag32[(s>>3)*108 + 100 + (s&7)] = 0u;
  }
  // stage x fragment-linear: sm_xf[lane][i] = B[k=(lane>>5)*8+i][lane&31]
  for (int s = t; s < 512; s += 256){
    int ln = s >> 3; int i = s & 7;
    int k = ((ln >> 5) << 3) + i;
    int agent = ln & 31;
    unsigned short v = 0;
    if (k < 12) v = f2b(x_flat[(ab+agent)*12 + k]);
    sm_xf[s] = v;
  }
  __syncthreads();

  // ---- B0 frags (all 11) cached in regs BEFORE the loop (proven-safe) ----
  const uint4* xfv = (const uint4*)sm_xf;
  const uint4* r0v = (const uint4*)(sm_ag + cl*216);
  bf16x8 B0[11];
  B0[0] = asb(xfv[lane]);
  #pragma unroll
  for (int ks=1; ks<11; ks++) B0[ks] = asb(r0v[(ks-1)*2 + hi]);
  __syncthreads();   // frag reads done: sm_xf dead, in-place h_new writes allowed

  // zero sm_h1 (cols 50..71 serve as MLP2 K-pad)
  for (int s = t; s < 1152; s += 256) ((unsigned*)sm_h1)[s] = 0u;

  // ---- GRU MFMA + gate epilogue (h_new in place, bf16) ----
  const uint4* ApV = (const uint4*)Apack;
  #pragma unroll 1
  for (int mt = w; mt < 19; mt += 4){
    f32x16 acc0;
    #pragma unroll
    for (int q=0;q<4;q++){
      float4 bq = ((const float4*)Bias4)[mt*8 + 2*q + hi];
      acc0[4*q+0]=bq.x; acc0[4*q+1]=bq.y; acc0[4*q+2]=bq.z; acc0[4*q+3]=bq.w;
    }
    const uint4* ap = ApV + (size_t)(mt*11)*64 + lane;
    #pragma unroll
    for (int ks=0; ks<11; ks++){
      acc0 = mfma32(asb(ap[ks*64]), B0[ks], acc0);
    }
    int a = cl;
    #pragma unroll
    for (int q=0;q<4;q++){
      int j = mt*8 + 2*q + hi;
      if (j < 150){
        float h0 = b2f(sm_ag[a*216 + j]);
        float r = fsigmoid(acc0[4*q+0]);
        float z = fsigmoid(acc0[4*q+1]);
        float n = ftanh(acc0[4*q+3] + r*acc0[4*q+2]);
        sm_ag[a*216 + j] = f2b(n + z*(h0 - n));
      }
    }
  }
  __syncthreads();

  // ---- flush h_new coalesced ----
  float2* oh2 = (float2*)(out + (size_t)8*NA);
  for (int s = t; s < 2400; s += 256){
    unsigned u = ag32[(s/75)*108 + (s - (s/75)*75)];
    float2 v; v.x = b2f((unsigned short)u); v.y = b2f((unsigned short)(u>>16));
    oh2[ab*75 + s] = v;
  }

  // ---- MLP1: 208 -> 50, softplus (waves 0,1; mt2 = w) ----
  if (w < 2){
    int mt2 = w;
    f32x16 acc;
    #pragma unroll
    for (int r=0;r<16;r++){
      int o = mt2*32 + (r&3) + 8*(r>>2) + 4*hi;
      acc[r] = (o < 50) ? b1[o] : 0.f;
    }
    {
      const uint4* rv  = (const uint4*)(sm_ag + cl*216);
      const uint4* w1v = (const uint4*)W1p;
      #pragma unroll
      for (int ks=0; ks<13; ks++){
        acc = mfma32(asb(w1v[(mt2*13+ks)*64 + lane]), asb(rv[ks*2+hi]), acc);
      }
    }
    #pragma unroll
    for (int r=0;r<16;r++){
      int o = mt2*32 + (r&3) + 8*(r>>2) + 4*hi;
      if (o < 50){
        float xx = acc[r];
        float spv = fmaxf(xx,0.f) + __logf(1.f + __expf(-fabsf(xx)));
        sm_h1[cl*72 + o] = f2b(spv);
      }
    }
  }
  __syncthreads();

  // ---- MLP2: 64 -> 50, tanh (waves 0,1) ----
  if (w < 2){
    int mt2 = w;
    f32x16 acc2;
    #pragma unroll
    for (int r=0;r<16;r++){
      int o = mt2*32 + (r&3) + 8*(r>>2) + 4*hi;
      acc2[r] = (o < 50) ? b2[o] : 0.f;
    }
    {
      const uint4* r1v = (const uint4*)(sm_h1 + cl*72);
      const uint4* w2v = (const uint4*)W2p;
      #pragma unroll
      for (int ks=0; ks<4; ks++){
        acc2 = mfma32(asb(w2v[(mt2*4+ks)*64 + lane]), asb(r1v[ks*2+hi]), acc2);
      }
    }
    #pragma unroll
    for (int r=0;r<16;r++){
      int o = mt2*32 + (r&3) + 8*(r>>2) + 4*hi;
      if (o < 50) sm_h2[cl*51 + o] = ftanh(acc2[r]);
    }
  }
  __syncthreads();

  // ---- head: 50 -> 6 + distribution math ----
  if (t < 32){
    int a = t; long ga = ab + a;
    float o6[6];
    #pragma unroll
    for (int jj=0;jj<6;jj++) o6[jj] = b3[jj];
    for (int k=0;k<50;k++){
      float v = sm_h2[a*51 + k];
      #pragma unroll
      for (int jj=0;jj<6;jj++) o6[jj] = fmaf(v, W3[jj*50+k], o6[jj]);
    }
    float mu0 = xp[ga*2+0] + 0.5f*dx[ga*2+0] + o6[0];
    float mu1 = xp[ga*2+1] + 0.5f*dx[ga*2+1] + o6[1];
    float bb  = o6[3] + o6[4];
    float apd = o6[2] + o6[5];
    float amd = o6[2] - o6[5];
    float delta = sqrtf(amd*amd + bb*bb);
    float e  = __expf(delta);
    float ei = 1.f/e;
    float sinh_ = 0.5f*(e - ei);
    float cosh_ = 0.5f*(e + ei);
    float tmp1 = sinh_/delta;
    float tmp2 = amd/tmp1;
    float ea = __expf(apd);
    float s00 = (cosh_+tmp2)*ea;
    float s01 = (bb*tmp1)*ea;
    float s11 = (cosh_-tmp2)*ea;
    float z0 = z_in[ga*2+0], z1 = z_in[ga*2+1];
    out[ga*2+0] = s00*z0 + s01*z1 + mu0;
    out[ga*2+1] = s01*z0 + s11*z1 + mu1;
    out[(size_t)2*NA + ga*2+0] = mu0;
    out[(size_t)2*NA + ga*2+1] = mu1;
    out[(size_t)4*NA + ga*4+0] = s00;
    out[(size_t)4*NA + ga*4+1] = s01;
    out[(size_t)4*NA + ga*4+2] = s01;
    out[(size_t)4*NA + ga*4+3] = s11;
  }
}

extern "C" void kernel_launch(void* const* d_in, const int* in_sizes, int n_in,
                              void* d_out, int out_size, void* d_ws, size_t ws_size,
                              hipStream_t stream) {
  const float* z      = (const float*)d_in[0];
  const float* x_flat = (const float*)d_in[1];
  const float* h      = (const float*)d_in[2];
  const float* st     = (const float*)d_in[3];
  const float* dx     = (const float*)d_in[4];
  const float* xp     = (const float*)d_in[5];
  const float* W_ih   = (const float*)d_in[6];
  const float* W_hh   = (const float*)d_in[7];
  const float* b_ih   = (const float*)d_in[8];
  const float* b_hh   = (const float*)d_in[9];
  const float* W1     = (const float*)d_in[10];
  const float* b1     = (const float*)d_in[11];
  const float* W2     = (const float*)d_in[12];
  const float* b2     = (const float*)d_in[13];
  const float* W3     = (const float*)d_in[14];
  const float* b3     = (const float*)d_in[15];
  float* out = (float*)d_out;
  float* ws  = (float*)d_ws;

  const unsigned short* Apack = (const unsigned short*)((char*)ws + APACK_OFF);
  const float*          Bias4 = (const float*)((char*)ws + BIAS4_OFF);
  const unsigned short* W1p   = (const unsigned short*)((char*)ws + W1P_OFF);
  const unsigned short* W2p   = (const unsigned short*)((char*)ws + W2P_OFF);

  hipLaunchKernelGGL(prep2, dim3(128), dim3(256), 0, stream,
                     W_ih, W_hh, b_ih, b_hh, W1, W2, ws);
  hipLaunchKernelGGL(fused_kernel, dim3(NBLK32), dim3(256), 0, stream,
                     x_flat, h, st, z, dx, xp, b1, b2, W3, b3,
                     Apack, Bias4, W1p, W2p, out);
}